// Round 5
// baseline (5434.774 us; speedup 1.0000x reference)
//
#include <hip/hip_runtime.h>

#define EMB 128
#define NBMAX 2048     // max buckets (etp: 1563)
#define BSHIFT 6       // 64 rows per bucket
#define TILE 8192      // entries per k_bin tile

typedef float v4f __attribute__((ext_vector_type(4)));
typedef short v8s __attribute__((ext_vector_type(8)));

__device__ inline float bf_lo(unsigned int u) { return __builtin_bit_cast(float, u << 16); }
__device__ inline float bf_hi(unsigned int u) { return __builtin_bit_cast(float, u & 0xffff0000u); }
__device__ inline unsigned short f2bf(float x) {
    unsigned int u = __builtin_bit_cast(unsigned int, x);
    return (unsigned short)((u + 0x7fffu + ((u >> 16) & 1u)) >> 16);   // RNE
}

// ---------------- A: bucket counts (LDS-privatized; ~0.5M global atomics total) ----------------
__global__ __launch_bounds__(256) void k_bcount(const int* __restrict__ rows, int n,
                                                int* __restrict__ cnt) {
    __shared__ int lh[NBMAX];
    for (int j = threadIdx.x; j < NBMAX; j += 256) lh[j] = 0;
    __syncthreads();
    for (int i = blockIdx.x * 256 + threadIdx.x; i < n; i += gridDim.x * 256)
        atomicAdd(&lh[rows[i] >> BSHIFT], 1);
    __syncthreads();
    for (int j = threadIdx.x; j < NBMAX; j += 256)
        if (lh[j]) atomicAdd(&cnt[j], lh[j]);
}

// ---------------- B: exclusive scan of NBMAX bucket counts -> bstart, bcur ----------------
__global__ __launch_bounds__(256) void k_bscan(const int* __restrict__ cnt,
                                               int* __restrict__ bstart, int* __restrict__ bcur) {
    __shared__ int wsum[4];
    __shared__ int wpre[4];
    int tid = threadIdx.x, lane = tid & 63, wv = tid >> 6;
    int v[8];
    int s = 0;
    #pragma unroll
    for (int k = 0; k < 8; ++k) { v[k] = cnt[tid * 8 + k]; s += v[k]; }
    int incl = s;
    #pragma unroll
    for (int off = 1; off < 64; off <<= 1) {
        int t = __shfl_up(incl, off);
        if (lane >= off) incl += t;
    }
    if (lane == 63) wsum[wv] = incl;
    __syncthreads();
    if (tid == 0) {
        int run = 0;
        #pragma unroll
        for (int w = 0; w < 4; ++w) { wpre[w] = run; run += wsum[w]; }
    }
    __syncthreads();
    int ex = wpre[wv] + incl - s;
    #pragma unroll
    for (int k = 0; k < 8; ++k) {
        int j = tid * 8 + k;
        bstart[j] = ex;
        bcur[j] = ex;
        ex += v[k];
    }
}

// ---------------- C: bin entries into bucket-contiguous e64 regions (tile counting-sort) ----------------
// e64 entry: bits[0:32) = (col<<15)|bf16val15, bits[32:38) = row low 6 bits; (staging adds bucket at bits 48+)
__global__ __launch_bounds__(256) void k_bin(const int* __restrict__ rows,
                                             const int* __restrict__ cols,
                                             const float* __restrict__ vals, int n,
                                             int* __restrict__ bcur,
                                             unsigned long long* __restrict__ e64) {
    __shared__ unsigned long long stage[TILE];   // 64 KB
    __shared__ int lh[NBMAX];                    // hist -> cursor
    __shared__ int lpos[NBMAX];                  // tile-local exclusive scan
    __shared__ int gbase[NBMAX];                 // reserved global base
    __shared__ int csum[NBMAX / 64];
    int tid = threadIdx.x, lane = tid & 63, wv = tid >> 6;
    int ntiles = (n + TILE - 1) / TILE;
    for (int tile = blockIdx.x; tile < ntiles; tile += gridDim.x) {
        int base = tile * TILE;
        int cnt_t = min(TILE, n - base);
        for (int j = tid; j < NBMAX; j += 256) lh[j] = 0;
        __syncthreads();
        // pass 1: tile histogram
        #pragma unroll 4
        for (int k = 0; k < TILE / 256; ++k) {
            int i = base + k * 256 + tid;
            if (i < n) atomicAdd(&lh[rows[i] >> BSHIFT], 1);
        }
        __syncthreads();
        // scan lh -> lpos (chunked wave scan: 32 chunks of 64)
        for (int c = wv; c < NBMAX / 64; c += 4) {
            int v = lh[c * 64 + lane];
            int incl = v;
            #pragma unroll
            for (int off = 1; off < 64; off <<= 1) {
                int t = __shfl_up(incl, off);
                if (lane >= off) incl += t;
            }
            lpos[c * 64 + lane] = incl - v;
            if (lane == 63) csum[c] = incl;
        }
        __syncthreads();
        if (tid < 64) {
            int v = (lane < NBMAX / 64) ? csum[lane] : 0;
            int incl = v;
            #pragma unroll
            for (int off = 1; off < 32; off <<= 1) {
                int t = __shfl_up(incl, off);
                if (lane >= off) incl += t;
            }
            if (lane < NBMAX / 64) csum[lane] = incl - v;
        }
        __syncthreads();
        // finalize lpos, reserve global chunks, init cursors (lh becomes cursor)
        for (int j = tid; j < NBMAX; j += 256) {
            int c0 = lh[j];
            int ex = lpos[j] + csum[j >> 6];
            lpos[j] = ex;
            lh[j] = ex;
            if (c0 > 0) gbase[j] = atomicAdd(&bcur[j], c0);
        }
        __syncthreads();
        // pass 2: place into stage (bucket-sorted within tile)
        #pragma unroll 4
        for (int k = 0; k < TILE / 256; ++k) {
            int i = base + k * 256 + tid;
            if (i < n) {
                int r = rows[i];
                int b = r >> BSHIFT;
                unsigned int lo = ((unsigned int)cols[i] << 15) | (unsigned int)f2bf(vals[i]);
                unsigned long long e = ((unsigned long long)(r & 63) << 32) | (unsigned long long)lo
                                     | ((unsigned long long)b << 48);
                int s = atomicAdd(&lh[b], 1);
                stage[s] = e;
            }
        }
        __syncthreads();
        // write out in bucket-sorted order (dense runs per bucket)
        for (int s = tid; s < cnt_t; s += 256) {
            unsigned long long e = stage[s];
            int b = (int)(e >> 48);
            e64[(size_t)gbase[b] + (s - lpos[b])] = e;
        }
        __syncthreads();
    }
}

// ---------------- fp32 -> bf16 table conversion ----------------
__global__ __launch_bounds__(256) void k_cvt(const float* __restrict__ src,
                                             unsigned short* __restrict__ dst, int n4) {
    int i = blockIdx.x * blockDim.x + threadIdx.x;
    if (i >= n4) return;
    v4f f = *(const v4f*)(src + (size_t)i * 4);
    ushort4 o;
    o.x = f2bf(f.x); o.y = f2bf(f.y); o.z = f2bf(f.z); o.w = f2bf(f.w);
    *(ushort4*)(dst + (size_t)i * 4) = o;
}

// ---------------- D: bucket-SpMM with LDS fp32 accumulators ----------------
// One block per bucket (64 rows x 128 cols fp32 = 32 KB LDS). Column-permuted accumulator:
// col c stored at (c>>1) + 64*(c&1)  ->  lane's two adds hit all 32 banks 2-way (free).
__global__ __launch_bounds__(512) void k_bspmm(const unsigned long long* __restrict__ e64,
                                               const int* __restrict__ bstart,
                                               const int* __restrict__ bcnt,
                                               const void* __restrict__ table,
                                               void* __restrict__ out,
                                               int nrows, int tbl_fp32, int out_fp32) {
    extern __shared__ float accs[];   // 64*128 floats
    int b = blockIdx.x;
    int r0 = b << BSHIFT;
    int nr = min(64, nrows - r0);
    int tid = threadIdx.x, lane = tid & 63, wv = tid >> 6;
    for (int j = tid; j < nr * EMB; j += 512) accs[j] = 0.f;
    __syncthreads();
    int beg = bstart[b], cnt = bcnt[b];
    const unsigned short* t16 = (const unsigned short*)table;
    const float* t32 = (const float*)table;
    for (int i = wv; i < cnt; i += 8) {
        unsigned long long e = e64[(size_t)beg + i];     // wave-uniform (broadcast)
        unsigned int lo = (unsigned int)e;
        int rloc = (int)((e >> 32) & 63);
        int c = (int)(lo >> 15);
        float v = __builtin_bit_cast(float, (lo & 0x7FFFu) << 16);
        float f0, f1;                                     // cols 2*lane, 2*lane+1
        if (tbl_fp32) {
            const float* fr = t32 + ((size_t)c << 7) + (lane << 1);
            float2 t = *(const float2*)fr;
            f0 = t.x; f1 = t.y;
        } else {
            unsigned int u = *(const unsigned int*)(t16 + ((size_t)c << 7) + (lane << 1));
            f0 = bf_lo(u); f1 = bf_hi(u);
        }
        float* arow = accs + rloc * EMB;
        atomicAdd(arow + lane, v * f0);          // col 2l   -> pos l
        atomicAdd(arow + 64 + lane, v * f1);     // col 2l+1 -> pos 64+l
    }
    __syncthreads();
    // un-permute + write (pair-unit j: row=j>>6, q=j&63 covers out cols 2q,2q+1)
    if (out_fp32) {
        float* po = (float*)out + ((size_t)r0 << 7);
        for (int j = tid; j < nr * 64; j += 512) {
            int row = j >> 6, q = j & 63;
            float2 t;
            t.x = accs[row * EMB + q];
            t.y = accs[row * EMB + 64 + q];
            *(float2*)(po + row * EMB + (q << 1)) = t;
        }
    } else {
        unsigned short* po = (unsigned short*)out + ((size_t)r0 << 7);
        for (int j = tid; j < nr * 64; j += 512) {
            int row = j >> 6, q = j & 63;
            unsigned int ov = (unsigned int)f2bf(accs[row * EMB + q])
                            | ((unsigned int)f2bf(accs[row * EMB + 64 + q]) << 16);
            *(unsigned int*)(po + row * EMB + (q << 1)) = ov;
        }
    }
}

// ---------------- weight prep: Wc = [Wp@Wf_top ; We@Wf_bot], B-fragment packed ----------------
// element (k,n) -> wc[((k>>3)*128 + n)*8 + (k&7)]
__global__ __launch_bounds__(128) void k_wprep(const float* __restrict__ Wp,
                                               const float* __restrict__ We,
                                               const float* __restrict__ Wf,
                                               unsigned short* __restrict__ wc) {
    int k = blockIdx.x;    // 0..255
    int n = threadIdx.x;   // 0..127
    const float* wrow = (k < 128) ? (Wp + (size_t)k * EMB) : (We + (size_t)(k - 128) * EMB);
    float acc = 0.f;
    #pragma unroll 4
    for (int j = 0; j < EMB; ++j)
        acc = fmaf(wrow[j], Wf[(size_t)((k < 128) ? j : (128 + j)) * EMB + n], acc);
    wc[(((k >> 3) * EMB) + n) * 8 + (k & 7)] = f2bf(acc);
}

// ---------------- fused GEMM (MFMA 16x16x32 bf16): M=nrows, K=256, N=128 ----------------
__global__ __launch_bounds__(256) void k_fused(const unsigned short* __restrict__ poi_agg,
                                               const float* __restrict__ edge,
                                               const unsigned short* __restrict__ wc,
                                               float* __restrict__ fused32, int nrows) {
    __shared__ __align__(16) unsigned short lds_w[32768];   // 64 KB packed B
    {
        const uint4* s = (const uint4*)wc;
        uint4* d = (uint4*)lds_w;
        #pragma unroll
        for (int i = 0; i < 16; ++i) d[threadIdx.x + i * 256] = s[threadIdx.x + i * 256];
    }
    __syncthreads();
    int lane = threadIdx.x & 63;
    int row_base = blockIdx.x * 64 + (threadIdx.x >> 6) * 16;
    int m = lane & 15, kq = lane >> 4;
    int arow = row_base + m;
    if (arow >= nrows) arow = nrows - 1;              // clamp reads; writes guarded
    const unsigned short* ap_p = poi_agg + (size_t)arow * EMB;
    const float* ap_e = edge + (size_t)arow * EMB;
    v4f zero = {0.f, 0.f, 0.f, 0.f};
    v4f acc[8];
    #pragma unroll
    for (int t = 0; t < 8; ++t) acc[t] = zero;
    #pragma unroll
    for (int kt = 0; kt < 8; ++kt) {
        v8s a;
        if (kt < 4) {
            a = *(const v8s*)(ap_p + kt * 32 + kq * 8);
        } else {
            int k0 = (kt - 4) * 32 + kq * 8;
            v4f f0 = *(const v4f*)(ap_e + k0);
            v4f f1 = *(const v4f*)(ap_e + k0 + 4);
            a[0] = (short)f2bf(f0.x); a[1] = (short)f2bf(f0.y);
            a[2] = (short)f2bf(f0.z); a[3] = (short)f2bf(f0.w);
            a[4] = (short)f2bf(f1.x); a[5] = (short)f2bf(f1.y);
            a[6] = (short)f2bf(f1.z); a[7] = (short)f2bf(f1.w);
        }
        int kk = kt * 4 + kq;
        #pragma unroll
        for (int nt = 0; nt < 8; ++nt) {
            v8s b = *(const v8s*)(lds_w + ((kk * EMB + nt * 16 + m) << 3));
            acc[nt] = __builtin_amdgcn_mfma_f32_16x16x32_bf16(a, b, acc[nt], 0, 0, 0);
        }
    }
    #pragma unroll
    for (int r = 0; r < 4; ++r) {
        int ro = row_base + kq * 4 + r;
        if (ro >= nrows) continue;
        #pragma unroll
        for (int nt = 0; nt < 8; ++nt)
            fused32[(size_t)ro * EMB + nt * 16 + m] = acc[nt][r];
    }
}

extern "C" void kernel_launch(void* const* d_in, const int* in_sizes, int n_in,
                              void* d_out, int out_size, void* d_ws, size_t ws_size,
                              hipStream_t stream) {
    const float* poi  = (const float*)d_in[0];
    const float* edge = (const float*)d_in[1];
    const int* pte_rows = (const int*)d_in[2];
    const int* pte_cols = (const int*)d_in[3];
    const float* pte_vals = (const float*)d_in[4];
    const int* etp_rows = (const int*)d_in[5];
    const int* etp_cols = (const int*)d_in[6];
    const float* etp_vals = (const float*)d_in[7];
    const float* Wp = (const float*)d_in[8];
    const float* We = (const float*)d_in[9];
    const float* Wf = (const float*)d_in[10];

    int n_poi  = in_sizes[0] / EMB;   // 100000
    int n_edge = in_sizes[1] / EMB;   // 50000
    int nnz1 = in_sizes[2];           // 3.2M (pte)
    int nnz2 = in_sizes[5];           // 3.2M (etp)

    // ---- workspace (~25.8 MB) ----
    char* ws = (char*)d_ws;
    size_t off = 0;
    auto alloc = [&](size_t bytes) -> char* {
        char* p = ws + off;
        off = (off + bytes + 255) & ~(size_t)255;
        return p;
    };
    int* bcnt   = (int*)alloc(NBMAX * 4);
    int* bstart = (int*)alloc(NBMAX * 4);
    int* bcur   = (int*)alloc(NBMAX * 4);
    unsigned short* wc = (unsigned short*)alloc((size_t)2 * EMB * EMB * 2);
    int nnz_max = (nnz1 > nnz2) ? nnz1 : nnz2;
    unsigned long long* e64 = (unsigned long long*)alloc((size_t)nnz_max * 8);  // reused pte -> etp

    // ---- d_out parking (output-0 region 51.2 MB fp32 written LAST by k_bspmm#2) ----
    float* out_prop  = (float*)d_out;                                   // [n_poi][128] fp32
    float* out_fused = out_prop + (size_t)n_poi * EMB;                  // [n_edge][128] fp32
    unsigned short* poi_bf  = (unsigned short*)d_out;                   // 25.6 MB bf16 (rows of poi)
    unsigned short* poi_agg = poi_bf + (size_t)n_poi * EMB;             // 12.8 MB bf16

    int nb1 = (n_edge + 63) >> BSHIFT;   // 782
    int nb2 = (n_poi + 63) >> BSHIFT;    // 1563
    size_t smem = (size_t)64 * EMB * 4;  // 32 KB

    // ---- pte CSR-lite: count -> scan -> bin ----
    hipMemsetAsync(bcnt, 0, NBMAX * 4, stream);
    k_bcount<<<256, 256, 0, stream>>>(pte_rows, nnz1, bcnt);
    k_bscan<<<1, 256, 0, stream>>>(bcnt, bstart, bcur);
    k_bin<<<256, 256, 0, stream>>>(pte_rows, pte_cols, pte_vals, nnz1, bcur, e64);

    k_cvt<<<(n_poi * EMB / 4 + 255) / 256, 256, 0, stream>>>(poi, poi_bf, n_poi * EMB / 4);
    k_wprep<<<256, 128, 0, stream>>>(Wp, We, Wf, wc);

    // spmm#1: poi_agg[e] = sum vals * poi[col]  (bf16 table, bf16 out)
    k_bspmm<<<nb1, 512, smem, stream>>>(e64, bstart, bcnt, poi_bf, poi_agg, n_edge, 0, 0);
    // fused = poi_agg @ (Wp@Wf_top) + edge @ (We@Wf_bot) -> output 1 (fp32)
    k_fused<<<(n_edge + 63) / 64, 256, 0, stream>>>(poi_agg, edge, wc, out_fused, n_edge);

    // ---- etp CSR-lite (e64 reused; runs after spmm#1 consumed pte bins) ----
    hipMemsetAsync(bcnt, 0, NBMAX * 4, stream);
    k_bcount<<<256, 256, 0, stream>>>(etp_rows, nnz2, bcnt);
    k_bscan<<<1, 256, 0, stream>>>(bcnt, bstart, bcur);
    k_bin<<<256, 256, 0, stream>>>(etp_rows, etp_cols, etp_vals, nnz2, bcur, e64);

    // spmm#2: propagated_poi = spmm(etp, fused) (fp32 table from out_fused, fp32 out)
    k_bspmm<<<nb2, 512, smem, stream>>>(e64, bstart, bcnt, out_fused, out_prop, n_poi, 1, 1);
}

// Round 6
// 710.720 us; speedup vs baseline: 7.6469x; 7.6469x over previous
//
#include <hip/hip_runtime.h>

#define EMB 128
#define NBMAX 2048     // max buckets (etp: 1563)
#define BSHIFT 6       // 64 rows per bucket
#define TILE 8192      // entries per k_bin tile
#define CHUNK 4096     // entries per k_bspmm LDS chunk

typedef float v4f __attribute__((ext_vector_type(4)));
typedef short v8s __attribute__((ext_vector_type(8)));

__device__ inline float bf_lo(unsigned int u) { return __builtin_bit_cast(float, u << 16); }
__device__ inline float bf_hi(unsigned int u) { return __builtin_bit_cast(float, u & 0xffff0000u); }
__device__ inline float bfv(unsigned int e) { return __builtin_bit_cast(float, (e & 0x7FFFu) << 16); }
__device__ inline unsigned short f2bf(float x) {
    unsigned int u = __builtin_bit_cast(unsigned int, x);
    return (unsigned short)((u + 0x7fffu + ((u >> 16) & 1u)) >> 16);   // RNE
}

// ---------------- A: bucket counts (LDS-privatized) ----------------
__global__ __launch_bounds__(256) void k_bcount(const int* __restrict__ rows, int n,
                                                int* __restrict__ cnt) {
    __shared__ int lh[NBMAX];
    for (int j = threadIdx.x; j < NBMAX; j += 256) lh[j] = 0;
    __syncthreads();
    for (int i = blockIdx.x * 256 + threadIdx.x; i < n; i += gridDim.x * 256)
        atomicAdd(&lh[rows[i] >> BSHIFT], 1);
    __syncthreads();
    for (int j = threadIdx.x; j < NBMAX; j += 256)
        if (lh[j]) atomicAdd(&cnt[j], lh[j]);
}

// ---------------- B: exclusive scan of NBMAX bucket counts -> bstart, bcur ----------------
__global__ __launch_bounds__(256) void k_bscan(const int* __restrict__ cnt,
                                               int* __restrict__ bstart, int* __restrict__ bcur) {
    __shared__ int wsum[4];
    __shared__ int wpre[4];
    int tid = threadIdx.x, lane = tid & 63, wv = tid >> 6;
    int v[8];
    int s = 0;
    #pragma unroll
    for (int k = 0; k < 8; ++k) { v[k] = cnt[tid * 8 + k]; s += v[k]; }
    int incl = s;
    #pragma unroll
    for (int off = 1; off < 64; off <<= 1) {
        int t = __shfl_up(incl, off);
        if (lane >= off) incl += t;
    }
    if (lane == 63) wsum[wv] = incl;
    __syncthreads();
    if (tid == 0) {
        int run = 0;
        #pragma unroll
        for (int w = 0; w < 4; ++w) { wpre[w] = run; run += wsum[w]; }
    }
    __syncthreads();
    int ex = wpre[wv] + incl - s;
    #pragma unroll
    for (int k = 0; k < 8; ++k) {
        int j = tid * 8 + k;
        bstart[j] = ex;
        bcur[j] = ex;
        ex += v[k];
    }
}

// ---------------- C: bin entries bucket-contiguous (tile counting-sort) ----------------
// e64: bits[0:32)=(col<<15)|bf16val15, bits[32:38)=row&63, bits[48:)=bucket
__global__ __launch_bounds__(256) void k_bin(const int* __restrict__ rows,
                                             const int* __restrict__ cols,
                                             const float* __restrict__ vals, int n,
                                             int* __restrict__ bcur,
                                             unsigned long long* __restrict__ e64) {
    __shared__ unsigned long long stage[TILE];   // 64 KB
    __shared__ int lh[NBMAX];
    __shared__ int lpos[NBMAX];
    __shared__ int gbase[NBMAX];
    __shared__ int csum[NBMAX / 64];
    int tid = threadIdx.x, lane = tid & 63, wv = tid >> 6;
    int ntiles = (n + TILE - 1) / TILE;
    for (int tile = blockIdx.x; tile < ntiles; tile += gridDim.x) {
        int base = tile * TILE;
        int cnt_t = min(TILE, n - base);
        for (int j = tid; j < NBMAX; j += 256) lh[j] = 0;
        __syncthreads();
        #pragma unroll 4
        for (int k = 0; k < TILE / 256; ++k) {
            int i = base + k * 256 + tid;
            if (i < n) atomicAdd(&lh[rows[i] >> BSHIFT], 1);
        }
        __syncthreads();
        for (int c = wv; c < NBMAX / 64; c += 4) {
            int v = lh[c * 64 + lane];
            int incl = v;
            #pragma unroll
            for (int off = 1; off < 64; off <<= 1) {
                int t = __shfl_up(incl, off);
                if (lane >= off) incl += t;
            }
            lpos[c * 64 + lane] = incl - v;
            if (lane == 63) csum[c] = incl;
        }
        __syncthreads();
        if (tid < 64) {
            int v = (lane < NBMAX / 64) ? csum[lane] : 0;
            int incl = v;
            #pragma unroll
            for (int off = 1; off < 32; off <<= 1) {
                int t = __shfl_up(incl, off);
                if (lane >= off) incl += t;
            }
            if (lane < NBMAX / 64) csum[lane] = incl - v;
        }
        __syncthreads();
        for (int j = tid; j < NBMAX; j += 256) {
            int c0 = lh[j];
            int ex = lpos[j] + csum[j >> 6];
            lpos[j] = ex;
            lh[j] = ex;
            if (c0 > 0) gbase[j] = atomicAdd(&bcur[j], c0);
        }
        __syncthreads();
        #pragma unroll 4
        for (int k = 0; k < TILE / 256; ++k) {
            int i = base + k * 256 + tid;
            if (i < n) {
                int r = rows[i];
                int b = r >> BSHIFT;
                unsigned int lo = ((unsigned int)cols[i] << 15) | (unsigned int)f2bf(vals[i]);
                unsigned long long e = ((unsigned long long)(r & 63) << 32) | (unsigned long long)lo
                                     | ((unsigned long long)b << 48);
                int s = atomicAdd(&lh[b], 1);
                stage[s] = e;
            }
        }
        __syncthreads();
        for (int s = tid; s < cnt_t; s += 256) {
            unsigned long long e = stage[s];
            int b = (int)(e >> 48);
            e64[(size_t)gbase[b] + (s - lpos[b])] = e;
        }
        __syncthreads();
    }
}

// ---------------- fp32 -> bf16 table conversion ----------------
__global__ __launch_bounds__(256) void k_cvt(const float* __restrict__ src,
                                             unsigned short* __restrict__ dst, int n4) {
    int i = blockIdx.x * blockDim.x + threadIdx.x;
    if (i >= n4) return;
    v4f f = *(const v4f*)(src + (size_t)i * 4);
    ushort4 o;
    o.x = f2bf(f.x); o.y = f2bf(f.y); o.z = f2bf(f.z); o.w = f2bf(f.w);
    *(ushort4*)(dst + (size_t)i * 4) = o;
}

// ---------------- D: bucket-SpMM, LDS row-sort + register accumulation ----------------
// One block per bucket. Chunk entries -> LDS sort by row (64 bins) -> each wave owns 8 rows,
// register acc, unroll-4 independent gathers (restores MLP lost in round 5).
__global__ __launch_bounds__(512) void k_bspmm(const unsigned long long* __restrict__ e64,
                                               const int* __restrict__ bstart,
                                               const int* __restrict__ bcnt,
                                               const void* __restrict__ table,
                                               void* __restrict__ out,
                                               int nrows, int tbl_fp32, int out_fp32) {
    __shared__ unsigned int ent[CHUNK];   // 16 KB
    __shared__ int rh[64];
    __shared__ int rptr[65];
    int b = blockIdx.x;
    int r0 = b << BSHIFT;
    int tid = threadIdx.x, lane = tid & 63, wv = tid >> 6;
    int beg = bstart[b], cnt = bcnt[b];
    const unsigned short* t16 = (const unsigned short*)table;
    const float* t32 = (const float*)table;
    float a0[8], a1[8];
    #pragma unroll
    for (int t = 0; t < 8; ++t) { a0[t] = 0.f; a1[t] = 0.f; }
    for (int cb = 0; cb < cnt; cb += CHUNK) {
        int cn = min(CHUNK, cnt - cb);
        if (tid < 64) rh[tid] = 0;
        __syncthreads();
        unsigned long long e[8];
        #pragma unroll
        for (int k = 0; k < 8; ++k) {
            int idx = k * 512 + tid;
            e[k] = 0ull;
            if (idx < cn) {
                e[k] = e64[(size_t)beg + cb + idx];
                atomicAdd(&rh[(int)(e[k] >> 32) & 63], 1);
            }
        }
        __syncthreads();
        if (tid < 64) {             // wave-0 scan of 64 row counts
            int v = rh[tid];
            int incl = v;
            #pragma unroll
            for (int off = 1; off < 64; off <<= 1) {
                int t = __shfl_up(incl, off);
                if (lane >= off) incl += t;
            }
            rptr[tid] = incl - v;
            if (tid == 63) rptr[64] = incl;
            rh[tid] = incl - v;     // becomes cursor
        }
        __syncthreads();
        #pragma unroll
        for (int k = 0; k < 8; ++k) {
            int idx = k * 512 + tid;
            if (idx < cn) {
                int row = (int)(e[k] >> 32) & 63;
                int p = atomicAdd(&rh[row], 1);
                ent[p] = (unsigned int)e[k];
            }
        }
        __syncthreads();
        // compute: wave wv owns local rows [wv*8, wv*8+8)
        #pragma unroll
        for (int t = 0; t < 8; ++t) {
            int l = wv * 8 + t;
            int j = rptr[l], je = rptr[l + 1];
            if (tbl_fp32) {
                for (; j + 4 <= je; j += 4) {
                    unsigned int e0 = ent[j], e1 = ent[j + 1], e2 = ent[j + 2], e3 = ent[j + 3];
                    float2 u0 = *(const float2*)(t32 + ((size_t)(e0 >> 15) << 7) + (lane << 1));
                    float2 u1 = *(const float2*)(t32 + ((size_t)(e1 >> 15) << 7) + (lane << 1));
                    float2 u2 = *(const float2*)(t32 + ((size_t)(e2 >> 15) << 7) + (lane << 1));
                    float2 u3 = *(const float2*)(t32 + ((size_t)(e3 >> 15) << 7) + (lane << 1));
                    a0[t] = fmaf(bfv(e0), u0.x, a0[t]); a1[t] = fmaf(bfv(e0), u0.y, a1[t]);
                    a0[t] = fmaf(bfv(e1), u1.x, a0[t]); a1[t] = fmaf(bfv(e1), u1.y, a1[t]);
                    a0[t] = fmaf(bfv(e2), u2.x, a0[t]); a1[t] = fmaf(bfv(e2), u2.y, a1[t]);
                    a0[t] = fmaf(bfv(e3), u3.x, a0[t]); a1[t] = fmaf(bfv(e3), u3.y, a1[t]);
                }
                for (; j < je; ++j) {
                    unsigned int e0 = ent[j];
                    float2 u0 = *(const float2*)(t32 + ((size_t)(e0 >> 15) << 7) + (lane << 1));
                    a0[t] = fmaf(bfv(e0), u0.x, a0[t]); a1[t] = fmaf(bfv(e0), u0.y, a1[t]);
                }
            } else {
                for (; j + 4 <= je; j += 4) {
                    unsigned int e0 = ent[j], e1 = ent[j + 1], e2 = ent[j + 2], e3 = ent[j + 3];
                    unsigned int u0 = *(const unsigned int*)(t16 + ((size_t)(e0 >> 15) << 7) + (lane << 1));
                    unsigned int u1 = *(const unsigned int*)(t16 + ((size_t)(e1 >> 15) << 7) + (lane << 1));
                    unsigned int u2 = *(const unsigned int*)(t16 + ((size_t)(e2 >> 15) << 7) + (lane << 1));
                    unsigned int u3 = *(const unsigned int*)(t16 + ((size_t)(e3 >> 15) << 7) + (lane << 1));
                    a0[t] = fmaf(bfv(e0), bf_lo(u0), a0[t]); a1[t] = fmaf(bfv(e0), bf_hi(u0), a1[t]);
                    a0[t] = fmaf(bfv(e1), bf_lo(u1), a0[t]); a1[t] = fmaf(bfv(e1), bf_hi(u1), a1[t]);
                    a0[t] = fmaf(bfv(e2), bf_lo(u2), a0[t]); a1[t] = fmaf(bfv(e2), bf_hi(u2), a1[t]);
                    a0[t] = fmaf(bfv(e3), bf_lo(u3), a0[t]); a1[t] = fmaf(bfv(e3), bf_hi(u3), a1[t]);
                }
                for (; j < je; ++j) {
                    unsigned int e0 = ent[j];
                    unsigned int u0 = *(const unsigned int*)(t16 + ((size_t)(e0 >> 15) << 7) + (lane << 1));
                    a0[t] = fmaf(bfv(e0), bf_lo(u0), a0[t]); a1[t] = fmaf(bfv(e0), bf_hi(u0), a1[t]);
                }
            }
        }
        __syncthreads();
    }
    int nr = min(64, nrows - r0);
    #pragma unroll
    for (int t = 0; t < 8; ++t) {
        int l = wv * 8 + t;
        if (l < nr) {
            if (out_fp32) {
                float2 o; o.x = a0[t]; o.y = a1[t];
                *(float2*)((float*)out + (((size_t)(r0 + l)) << 7) + (lane << 1)) = o;
            } else {
                unsigned int ov = (unsigned int)f2bf(a0[t]) | ((unsigned int)f2bf(a1[t]) << 16);
                *(unsigned int*)((unsigned short*)out + (((size_t)(r0 + l)) << 7) + (lane << 1)) = ov;
            }
        }
    }
}

// ---------------- weight prep: Wc = [Wp@Wf_top ; We@Wf_bot], B-fragment packed ----------------
__global__ __launch_bounds__(128) void k_wprep(const float* __restrict__ Wp,
                                               const float* __restrict__ We,
                                               const float* __restrict__ Wf,
                                               unsigned short* __restrict__ wc) {
    int k = blockIdx.x;    // 0..255
    int n = threadIdx.x;   // 0..127
    const float* wrow = (k < 128) ? (Wp + (size_t)k * EMB) : (We + (size_t)(k - 128) * EMB);
    float acc = 0.f;
    #pragma unroll 4
    for (int j = 0; j < EMB; ++j)
        acc = fmaf(wrow[j], Wf[(size_t)((k < 128) ? j : (128 + j)) * EMB + n], acc);
    wc[(((k >> 3) * EMB) + n) * 8 + (k & 7)] = f2bf(acc);
}

// ---------------- fused GEMM (MFMA 16x16x32 bf16): M=nrows, K=256, N=128 ----------------
__global__ __launch_bounds__(256) void k_fused(const unsigned short* __restrict__ poi_agg,
                                               const float* __restrict__ edge,
                                               const unsigned short* __restrict__ wc,
                                               float* __restrict__ fused32,
                                               unsigned short* __restrict__ fused16, int nrows) {
    __shared__ __align__(16) unsigned short lds_w[32768];   // 64 KB packed B
    {
        const uint4* s = (const uint4*)wc;
        uint4* d = (uint4*)lds_w;
        #pragma unroll
        for (int i = 0; i < 16; ++i) d[threadIdx.x + i * 256] = s[threadIdx.x + i * 256];
    }
    __syncthreads();
    int lane = threadIdx.x & 63;
    int row_base = blockIdx.x * 64 + (threadIdx.x >> 6) * 16;
    int m = lane & 15, kq = lane >> 4;
    int arow = row_base + m;
    if (arow >= nrows) arow = nrows - 1;
    const unsigned short* ap_p = poi_agg + (size_t)arow * EMB;
    const float* ap_e = edge + (size_t)arow * EMB;
    v4f zero = {0.f, 0.f, 0.f, 0.f};
    v4f acc[8];
    #pragma unroll
    for (int t = 0; t < 8; ++t) acc[t] = zero;
    #pragma unroll
    for (int kt = 0; kt < 8; ++kt) {
        v8s a;
        if (kt < 4) {
            a = *(const v8s*)(ap_p + kt * 32 + kq * 8);
        } else {
            int k0 = (kt - 4) * 32 + kq * 8;
            v4f f0 = *(const v4f*)(ap_e + k0);
            v4f f1 = *(const v4f*)(ap_e + k0 + 4);
            a[0] = (short)f2bf(f0.x); a[1] = (short)f2bf(f0.y);
            a[2] = (short)f2bf(f0.z); a[3] = (short)f2bf(f0.w);
            a[4] = (short)f2bf(f1.x); a[5] = (short)f2bf(f1.y);
            a[6] = (short)f2bf(f1.z); a[7] = (short)f2bf(f1.w);
        }
        int kk = kt * 4 + kq;
        #pragma unroll
        for (int nt = 0; nt < 8; ++nt) {
            v8s bfr = *(const v8s*)(lds_w + ((kk * EMB + nt * 16 + m) << 3));
            acc[nt] = __builtin_amdgcn_mfma_f32_16x16x32_bf16(a, bfr, acc[nt], 0, 0, 0);
        }
    }
    #pragma unroll
    for (int r = 0; r < 4; ++r) {
        int ro = row_base + kq * 4 + r;
        if (ro >= nrows) continue;
        #pragma unroll
        for (int nt = 0; nt < 8; ++nt) {
            float x = acc[nt][r];
            size_t o = (size_t)ro * EMB + nt * 16 + m;
            fused32[o] = x;
            if (fused16) fused16[o] = f2bf(x);
        }
    }
}

extern "C" void kernel_launch(void* const* d_in, const int* in_sizes, int n_in,
                              void* d_out, int out_size, void* d_ws, size_t ws_size,
                              hipStream_t stream) {
    const float* poi  = (const float*)d_in[0];
    const float* edge = (const float*)d_in[1];
    const int* pte_rows = (const int*)d_in[2];
    const int* pte_cols = (const int*)d_in[3];
    const float* pte_vals = (const float*)d_in[4];
    const int* etp_rows = (const int*)d_in[5];
    const int* etp_cols = (const int*)d_in[6];
    const float* etp_vals = (const float*)d_in[7];
    const float* Wp = (const float*)d_in[8];
    const float* We = (const float*)d_in[9];
    const float* Wf = (const float*)d_in[10];

    int n_poi  = in_sizes[0] / EMB;   // 100000
    int n_edge = in_sizes[1] / EMB;   // 50000
    int nnz1 = in_sizes[2];           // 3.2M
    int nnz2 = in_sizes[5];           // 3.2M

    char* ws = (char*)d_ws;
    size_t off = 0;
    auto alloc = [&](size_t bytes) -> char* {
        char* p = ws + off;
        off = (off + bytes + 255) & ~(size_t)255;
        return p;
    };
    int* bcnt   = (int*)alloc(NBMAX * 4);
    int* bstart = (int*)alloc(NBMAX * 4);
    int* bcur   = (int*)alloc(NBMAX * 4);
    unsigned short* wc = (unsigned short*)alloc((size_t)2 * EMB * EMB * 2);
    int nnz_max = (nnz1 > nnz2) ? nnz1 : nnz2;
    unsigned long long* e64 = (unsigned long long*)alloc((size_t)nnz_max * 8);  // reused pte -> etp
    // optional bf16 copy of fused (halves spmm#2 gather bytes) — only if ws allows
    size_t f16_bytes = (size_t)n_edge * EMB * 2;
    unsigned short* fused16 = nullptr;
    if (off + f16_bytes <= ws_size) fused16 = (unsigned short*)alloc(f16_bytes);

    // d_out parking: output-0 region (51.2 MB) holds poi_bf + poi_agg until spmm#2
    float* out_prop  = (float*)d_out;                                   // [n_poi][128] fp32
    float* out_fused = out_prop + (size_t)n_poi * EMB;                  // [n_edge][128] fp32
    unsigned short* poi_bf  = (unsigned short*)d_out;                   // 25.6 MB bf16
    unsigned short* poi_agg = poi_bf + (size_t)n_poi * EMB;             // 12.8 MB bf16

    int nb1 = (n_edge + 63) >> BSHIFT;   // 782
    int nb2 = (n_poi + 63) >> BSHIFT;    // 1563

    // ---- pte binning ----
    hipMemsetAsync(bcnt, 0, NBMAX * 4, stream);
    k_bcount<<<256, 256, 0, stream>>>(pte_rows, nnz1, bcnt);
    k_bscan<<<1, 256, 0, stream>>>(bcnt, bstart, bcur);
    k_bin<<<256, 256, 0, stream>>>(pte_rows, pte_cols, pte_vals, nnz1, bcur, e64);

    k_cvt<<<(n_poi * EMB / 4 + 255) / 256, 256, 0, stream>>>(poi, poi_bf, n_poi * EMB / 4);
    k_wprep<<<256, 128, 0, stream>>>(Wp, We, Wf, wc);

    // spmm#1: poi_agg[e] = sum vals * poi[col]  (bf16 table -> bf16 out)
    k_bspmm<<<nb1, 512, 0, stream>>>(e64, bstart, bcnt, poi_bf, poi_agg, n_edge, 0, 0);
    // fused = poi_agg @ (Wp@Wf_top) + edge @ (We@Wf_bot) -> output 1 (fp32) [+ bf16 copy]
    k_fused<<<(n_edge + 63) / 64, 256, 0, stream>>>(poi_agg, edge, wc, out_fused, fused16, n_edge);

    // ---- etp binning (e64 reused after spmm#1 consumed it) ----
    hipMemsetAsync(bcnt, 0, NBMAX * 4, stream);
    k_bcount<<<256, 256, 0, stream>>>(etp_rows, nnz2, bcnt);
    k_bscan<<<1, 256, 0, stream>>>(bcnt, bstart, bcur);
    k_bin<<<256, 256, 0, stream>>>(etp_rows, etp_cols, etp_vals, nnz2, bcur, e64);

    // spmm#2: propagated_poi = spmm(etp, fused) -> output 0 (fp32)
    if (fused16)
        k_bspmm<<<nb2, 512, 0, stream>>>(e64, bstart, bcnt, fused16, out_prop, n_poi, 0, 1);
    else
        k_bspmm<<<nb2, 512, 0, stream>>>(e64, bstart, bcnt, out_fused, out_prop, n_poi, 1, 1);
}